// Round 2
// baseline (694.586 us; speedup 1.0000x reference)
//
#include <hip/hip_runtime.h>
#include <math.h>

constexpr int N = 10000;   // nodes
constexpr int E = 50000;   // edges
constexpr int D = 32;      // dim
constexpr int H = 4;       // heads

typedef float v4f __attribute__((ext_vector_type(4)));

__device__ __forceinline__ v4f ntload(const float* p) {
    return __builtin_nontemporal_load(reinterpret_cast<const v4f*>(p));
}

// ---------------------------------------------------------------------------
// Edge kernel: TWO edges per 256-thread block (halves block count, doubles
// per-thread memory-level parallelism: 8 outstanding 16B weight loads).
// Per-edge hypernetwork matvecs + logit + exp, then ATOMIC accumulation of
// exp (denominator) and exp*V (unnormalized aggregate) into per-node
// buffers. Softmax normalization commutes with the weighted sum, so no
// CSR / edge-list pass is needed.
//
// Thread t: hd = t>>3 (0..31 = h*8+d_local), seg = t&7. Wave w == head w.
// ---------------------------------------------------------------------------
__global__ __launch_bounds__(256) void edge_kernel(
    const float* __restrict__ in_feat,
    const int*   __restrict__ src, const int* __restrict__ dst,
    const float* __restrict__ skw, const float* __restrict__ dkw,
    const float* __restrict__ skb, const float* __restrict__ dkb,
    const float* __restrict__ svw, const float* __restrict__ dvw,
    const float* __restrict__ svb, const float* __restrict__ dvb,
    const float* __restrict__ query,
    float* __restrict__ key_feat, float* __restrict__ value_feat,
    float* __restrict__ ex_out,   // attn slot of d_out; holds exp(logit)
    float* __restrict__ aggU,     // (N, D) unnormalized aggregate (= out slot)
    float* __restrict__ denom)    // (N, H) softmax denominator (workspace)
{
    const int e0  = blockIdx.x * 2;
    const int e1  = e0 + 1;
    const int tid = threadIdx.x;
    const int hd  = tid >> 3;   // 0..31  (= h*8 + d_local)
    const int seg = tid & 7;    // 0..7

    const int s0 = src[e0], d0 = dst[e0];
    const int s1 = src[e1], d1 = dst[e1];

    // issue all 8 read-once weight loads first (max MLP), nontemporal
    const size_t w0 = (size_t)e0 * 1024 + (size_t)tid * 4;
    const size_t w1 = w0 + 1024;
    const v4f ka0 = ntload(skw + w0);
    const v4f kb0 = ntload(dkw + w0);
    const v4f va0 = ntload(svw + w0);
    const v4f vb0 = ntload(dvw + w0);
    const v4f ka1 = ntload(skw + w1);
    const v4f kb1 = ntload(dkw + w1);
    const v4f va1 = ntload(svw + w1);
    const v4f vb1 = ntload(dvw + w1);

    // node features: L2/L3-resident gathers (1.28 MB table)
    const float4 u0 = *reinterpret_cast<const float4*>(in_feat + s0 * D + seg * 4);
    const float4 x0 = *reinterpret_cast<const float4*>(in_feat + d0 * D + seg * 4);
    const float4 u1 = *reinterpret_cast<const float4*>(in_feat + s1 * D + seg * 4);
    const float4 x1 = *reinterpret_cast<const float4*>(in_feat + d1 * D + seg * 4);

    float pk0 = ka0.x * u0.x + ka0.y * u0.y + ka0.z * u0.z + ka0.w * u0.w
              + kb0.x * x0.x + kb0.y * x0.y + kb0.z * x0.z + kb0.w * x0.w;
    float pv0 = va0.x * u0.x + va0.y * u0.y + va0.z * u0.z + va0.w * u0.w
              + vb0.x * x0.x + vb0.y * x0.y + vb0.z * x0.z + vb0.w * x0.w;
    float pk1 = ka1.x * u1.x + ka1.y * u1.y + ka1.z * u1.z + ka1.w * u1.w
              + kb1.x * x1.x + kb1.y * x1.y + kb1.z * x1.z + kb1.w * x1.w;
    float pv1 = va1.x * u1.x + va1.y * u1.y + va1.z * u1.z + va1.w * u1.w
              + vb1.x * x1.x + vb1.y * x1.y + vb1.z * x1.z + vb1.w * x1.w;

    #pragma unroll
    for (int off = 1; off < 8; off <<= 1) {
        pk0 += __shfl_xor(pk0, off);
        pv0 += __shfl_xor(pv0, off);
        pk1 += __shfl_xor(pk1, off);
        pv1 += __shfl_xor(pv1, off);
    }

    // only seg==0 lanes need biases / K / V / query
    const int bi0 = e0 * D + hd;
    const int bi1 = e1 * D + hd;
    float c0 = 0.0f, c1 = 0.0f, Vv0 = 0.0f, Vv1 = 0.0f;
    if (seg == 0) {
        const float K0 = pk0 + skb[bi0] + dkb[bi0];
        Vv0            = pv0 + svb[bi0] + dvb[bi0];
        const float K1 = pk1 + skb[bi1] + dkb[bi1];
        Vv1            = pv1 + svb[bi1] + dvb[bi1];
        __builtin_nontemporal_store(K0,  key_feat   + bi0);
        __builtin_nontemporal_store(Vv0, value_feat + bi0);
        __builtin_nontemporal_store(K1,  key_feat   + bi1);
        __builtin_nontemporal_store(Vv1, value_feat + bi1);
        c0 = K0 * query[d0 * D + hd];
        c1 = K1 * query[d1 * D + hd];
    }
    // seg==0 lanes (0,8,..,56) are closed under xor of bits 3..5: every seg0
    // lane of the wave ends with the full per-head logit.
    #pragma unroll
    for (int off = 8; off < 64; off <<= 1) {
        c0 += __shfl_xor(c0, off);
        c1 += __shfl_xor(c1, off);
    }

    if (seg == 0) {
        // softmax is shift-invariant; logits ~N(0,~1) -> expf safe in f32
        const float ex0 = expf(c0);
        const float ex1 = expf(c1);
        atomicAdd(aggU + d0 * D + hd, ex0 * Vv0);
        atomicAdd(aggU + d1 * D + hd, ex1 * Vv1);
        if ((tid & 63) == 0) {
            const int h = tid >> 6;          // wave index == head
            ex_out[e0 * H + h] = ex0;        // normalized later
            ex_out[e1 * H + h] = ex1;
            atomicAdd(denom + d0 * H + h, ex0);
            atomicAdd(denom + d1 * H + h, ex1);
        }
    }
}

// ---------------------------------------------------------------------------
// Fused node + attn kernel (one dispatch).
// Blocks [0, N/4): one wave per node. agg = aggU * (1/denom), node matvec +
//   relu + residual + layernorm. aggU lives in the `out` region of d_out:
//   each wave reads its own node's aggregate before overwriting it.
// Blocks [N/4, N/4 + ceil(E/256)): attn[e,h] = ex[e,h] / denom[dst[e],h],
//   one float4 RMW per thread.
// ---------------------------------------------------------------------------
constexpr int NODE_BLOCKS = N / 4;            // 2500 (N % 4 == 0)
constexpr int ATTN_BLOCKS = (E + 255) / 256;  // 196

__global__ __launch_bounds__(256) void node_attn_kernel(
    const int*   __restrict__ dst,
    const float* __restrict__ in_feat, const float* __restrict__ denom,
    const float* __restrict__ node_w,  const float* __restrict__ node_b,
    const float* __restrict__ ln_w,    const float* __restrict__ ln_b,
    float* __restrict__ attn,  // holds exp(logit) on entry, attn on exit
    float* __restrict__ out)   // holds aggU on entry, final output on exit
{
    if (blockIdx.x >= NODE_BLOCKS) {
        // ---- attn normalization part ----
        const int e = (blockIdx.x - NODE_BLOCKS) * 256 + threadIdx.x;
        if (e < E) {
            const int d = dst[e];
            const float4 ex = *reinterpret_cast<const float4*>(attn + (size_t)e * H);
            const float4 dn = *reinterpret_cast<const float4*>(denom + (size_t)d * H);
            float4 r;
            r.x = ex.x / dn.x;
            r.y = ex.y / dn.y;
            r.z = ex.z / dn.z;
            r.w = ex.w / dn.w;
            *reinterpret_cast<float4*>(attn + (size_t)e * H) = r;
        }
        return;
    }

    // ---- node part: one wave per node ----
    __shared__ float agg_sh[4][33];
    const int wave = threadIdx.x >> 6;
    const int lane = threadIdx.x & 63;
    const int n = blockIdx.x * 4 + wave;

    const int hd = lane & 31;   // 0..31: agg element (h*8+d)
    const int h  = hd >> 3;

    const float ds   = denom[n * H + h];
    const float rden = (ds != 0.0f) ? 1.0f / ds : 0.0f;  // deg==0 -> agg 0
    agg_sh[wave][hd] = out[n * D + hd] * rden;  // lanes 32..63 dup, same value
    __syncthreads();

    // matvec: o = lane>>1, half = lane&1 covers i in [half*16, half*16+16)
    const int o = lane >> 1, half = lane & 1;
    const float* w = node_w + (size_t)n * 1024 + o * 32 + half * 16;
    const float* g = &agg_sh[wave][half * 16];
    float p = 0.0f;
    #pragma unroll
    for (int j = 0; j < 16; j += 4) {
        const float4 wv = *reinterpret_cast<const float4*>(w + j);
        p += wv.x * g[j] + wv.y * g[j + 1] + wv.z * g[j + 2] + wv.w * g[j + 3];
    }
    p += __shfl_xor(p, 1);   // full dot on both lanes of the pair

    const float r = in_feat[n * D + o] + fmaxf(p + node_b[n * D + o], 0.0f);

    float sum = r, sq = r * r;
    #pragma unroll
    for (int off = 2; off < 64; off <<= 1) {
        sum += __shfl_xor(sum, off);
        sq  += __shfl_xor(sq, off);
    }
    const float mean = sum * (1.0f / 32.0f);
    const float var  = sq * (1.0f / 32.0f) - mean * mean;
    const float y = (r - mean) * rsqrtf(var + 1e-5f) * ln_w[o] + ln_b[o];
    if (half == 0) out[n * D + o] = y;
}

// ---------------------------------------------------------------------------
extern "C" void kernel_launch(void* const* d_in, const int* in_sizes, int n_in,
                              void* d_out, int out_size, void* d_ws, size_t ws_size,
                              hipStream_t stream)
{
    const float* in_feat = (const float*)d_in[0];
    const int*   src     = (const int*)d_in[1];
    const int*   dst     = (const int*)d_in[2];
    const float* skw     = (const float*)d_in[3];
    const float* dkw     = (const float*)d_in[4];
    const float* skb     = (const float*)d_in[5];
    const float* dkb     = (const float*)d_in[6];
    const float* svw     = (const float*)d_in[7];
    const float* dvw     = (const float*)d_in[8];
    const float* svb     = (const float*)d_in[9];
    const float* dvb     = (const float*)d_in[10];
    const float* query   = (const float*)d_in[11];
    const float* node_w  = (const float*)d_in[12];
    const float* node_b  = (const float*)d_in[13];
    const float* ln_w    = (const float*)d_in[14];
    const float* ln_b    = (const float*)d_in[15];

    // d_out layout: out(N*D) | key_feat(E*D) | value_feat(E*D) | attn(E*H)
    float* out        = (float*)d_out;
    float* key_feat   = out + (size_t)N * D;
    float* value_feat = key_feat + (size_t)E * D;
    float* attn       = value_feat + (size_t)E * D;

    // ws layout (floats): denom[N*H] only (160 KB)
    float* denom = (float*)d_ws;

    // zero the aggregation scratch (out region doubles as aggU) + denominators
    hipMemsetAsync(out,   0, (size_t)N * D * sizeof(float), stream);
    hipMemsetAsync(denom, 0, (size_t)N * H * sizeof(float), stream);

    edge_kernel<<<E / 2, 256, 0, stream>>>(in_feat, src, dst,
                                           skw, dkw, skb, dkb,
                                           svw, dvw, svb, dvb,
                                           query, key_feat, value_feat, attn,
                                           out, denom);

    node_attn_kernel<<<NODE_BLOCKS + ATTN_BLOCKS, 256, 0, stream>>>(
        dst, in_feat, denom, node_w, node_b, ln_w, ln_b, attn, out);
}